// Round 10
// baseline (58.105 us; speedup 1.0000x reference)
//
#include <hip/hip_runtime.h>
#include <hip/hip_cooperative_groups.h>

namespace cg = cooperative_groups;

#define NPTS   384
#define DIM    256
#define GA     6              // anchors per block
#define NBLK   64             // blocks (all co-resident; cooperative)
#define NTHR   512            // 8 waves
#define MAXK   64             // cap on same-class count (expected ~12)
#define MARGIN 1.0f

__device__ __forceinline__ float wave_red_sum(float p) {
    #pragma unroll
    for (int m = 1; m < 64; m <<= 1) p += __shfl_xor(p, m, 64);
    return p;
}

// Single cooperative kernel. Block b owns anchors [6b, 6b+6).
//  - 6 anchor fragments in registers; each of the 384 rows loaded once per
//    block and dotted vs all 6 anchors (quarter-wave 16-lane dots)
//  - dj[a][*] holds the FULL d-row -> positives are dj[a][kidx[a][t]], free
//  - waves 0..5 ballot-compact positives of anchor a0+w (global label reads,
//    concurrent with nothing dependent; one barrier total before hinge)
//  - hinge per thread-j, block reduce, partial[b] store, grid.sync(),
//    block 0 reduces 64 partials -> out. No tickets, no memset, no 2nd launch.
__global__ __launch_bounds__(NTHR) void triplet_coop(const float* __restrict__ x,
                                                     const int* __restrict__ labels,
                                                     float2* __restrict__ partial,
                                                     float* __restrict__ out) {
    const int b    = blockIdx.x;
    const int tid  = threadIdx.x;
    const int lane = tid & 63;
    const int wid  = tid >> 6;    // 0..7
    const int sub  = lane >> 4;   // row within 4-row group
    const int l16  = lane & 15;   // element-slice lane
    const int a0   = b * GA;

    __shared__ int   lab[NPTS];
    __shared__ float dj[GA][NPTS];
    __shared__ int   kidx[GA][MAXK];
    __shared__ int   nk_sh[GA];
    __shared__ float wnum[8], wcnt[8];

    for (int j = tid; j < NPTS; j += NTHR) lab[j] = labels[j];

    // anchor fragments: fa[t][q] = x[a0+t][l16*4 + q*64 .. +4)
    float4 fa[GA][4];
    #pragma unroll
    for (int t = 0; t < GA; ++t)
        #pragma unroll
        for (int q = 0; q < 4; ++q)
            fa[t][q] = *(const float4*)(x + (size_t)(a0 + t) * DIM + l16 * 4 + q * 64);

    // waves 0..5: ballot-compact positives of anchor a0+wid (global reads)
    if (wid < GA) {
        const int li = labels[a0 + wid];
        int base = 0;
        #pragma unroll
        for (int c = 0; c < 6; ++c) {
            const bool m = (labels[c * 64 + lane] == li);
            const unsigned long long mk = __ballot(m);
            const int pre = __popcll(mk & ((1ull << lane) - 1ull));
            const int p = base + pre;
            if (m && p < MAXK) kidx[wid][p] = c * 64 + lane;
            base += __popcll(mk);          // wave-uniform
        }
        if (lane == 0) nk_sh[wid] = (base > MAXK) ? MAXK : base;
    }

    // dots: 8 waves x 4 rows = 32 rows/iter, 12 iters; one load -> 6 dots
    #pragma unroll 2
    for (int u = 0; u < NPTS / 32; ++u) {
        const int r = u * 32 + wid * 4 + sub;
        const float* xr = x + (size_t)r * DIM + l16 * 4;
        float4 rx[4];
        #pragma unroll
        for (int q = 0; q < 4; ++q) rx[q] = *(const float4*)(xr + q * 64);
        #pragma unroll
        for (int t = 0; t < GA; ++t) {
            float acc = 0.f;
            #pragma unroll
            for (int q = 0; q < 4; ++q) {
                const float d0 = rx[q].x - fa[t][q].x, d1 = rx[q].y - fa[t][q].y,
                            d2 = rx[q].z - fa[t][q].z, d3 = rx[q].w - fa[t][q].w;
                acc += d0*d0 + d1*d1 + d2*d2 + d3*d3;
            }
            #pragma unroll
            for (int m = 1; m < 16; m <<= 1) acc += __shfl_xor(acc, m, 64);
            if (l16 == 0) dj[t][r] = acc;
        }
    }
    __syncthreads();

    // hinge: thread j = tid (tid<384); positives read from dj via kidx
    float num = 0.f, cnt = 0.f;
    if (tid < NPTS) {
        #pragma unroll
        for (int a = 0; a < GA; ++a) {
            const int li = lab[a0 + a];
            if (lab[tid] != li) {
                const float bb = dj[a][tid] - MARGIN;
                const int nk = nk_sh[a];
                for (int t = 0; t < nk; ++t) {
                    const float h = bb + dj[a][kidx[a][t]];  // uniform broadcasts
                    num += (h > 0.f) ? h : 0.f;
                }
                cnt += (float)nk;
            }
        }
    }
    num = wave_red_sum(num);
    cnt = wave_red_sum(cnt);
    if (lane == 0) { wnum[wid] = num; wcnt[wid] = cnt; }
    __syncthreads();
    if (tid == 0) {
        float n = 0.f, c = 0.f;
        #pragma unroll
        for (int w = 0; w < 8; ++w) { n += wnum[w]; c += wcnt[w]; }
        partial[b] = make_float2(n, c);
    }

    cg::this_grid().sync();

    if (b == 0 && tid < 64) {
        const float2 v = partial[tid];       // NBLK == 64 == one wave
        float n = v.x, c = v.y;
        #pragma unroll
        for (int m = 1; m < 64; m <<= 1) {
            n += __shfl_xor(n, m, 64);
            c += __shfl_xor(c, m, 64);
        }
        if (tid == 0) out[0] = n / c;
    }
}

extern "C" void kernel_launch(void* const* d_in, const int* in_sizes, int n_in,
                              void* d_out, int out_size, void* d_ws, size_t ws_size,
                              hipStream_t stream) {
    const float* x      = (const float*)d_in[0];
    const int*   labels = (const int*)d_in[1];
    float*       out    = (float*)d_out;
    float2*      partial = (float2*)d_ws;

    void* args[] = {(void*)&x, (void*)&labels, (void*)&partial, (void*)&out};
    hipLaunchCooperativeKernel((const void*)triplet_coop, dim3(NBLK), dim3(NTHR),
                               args, 0, stream);
}

// Round 11
// 24.341 us; speedup vs baseline: 2.3871x; 2.3871x over previous
//
#include <hip/hip_runtime.h>

#define NPTS   384
#define DIM    256
#define GA     4              // anchors per block (register-resident fragments)
#define NGRP   (NPTS/GA)      // 96 anchor groups
#define SPLIT  16             // j-slices
#define JS     (NPTS/SPLIT)   // 24 j's per block
#define NBLK   (NGRP*SPLIT)   // 1536 blocks = 6/CU
#define MAXK   64             // cap on same-class count (expected ~12)
#define MARGIN 1.0f

__device__ __forceinline__ float wave_red_sum(float p) {
    #pragma unroll
    for (int m = 1; m < 64; m <<= 1) p += __shfl_xor(p, m, 64);
    return p;
}

// Block (g, s): anchors a0..a0+3, j-slice s (24 rows). R9 structure with
// doubled block spread (6/CU): 4x register reuse per row AND full occupancy.
__global__ __launch_bounds__(256) void triplet_main(const float* __restrict__ x,
                                                    const int* __restrict__ labels,
                                                    float2* __restrict__ partial) {
    const int g    = blockIdx.x;
    const int s    = blockIdx.y;
    const int tid  = threadIdx.x;
    const int lane = tid & 63;
    const int wid  = tid >> 6;
    const int sub  = lane >> 4;   // row within 4-row group
    const int l16  = lane & 15;   // element-slice lane
    const int a0   = g * GA;

    __shared__ int   lab[NPTS];
    __shared__ int   kidx[GA][MAXK];
    __shared__ float dk[GA][MAXK];
    __shared__ float dj[GA][JS];
    __shared__ int   nk_sh[GA];
    __shared__ float wnum[2], wcnt[2];

    // stage labels for the hinge phase (all threads, strided)
    for (int j = tid; j < NPTS; j += 256) lab[j] = labels[j];

    // anchor fragments: fa[t][q] = x[a0+t][l16*4 + q*64 .. +4)
    float4 fa[GA][4];
    #pragma unroll
    for (int t = 0; t < GA; ++t)
        #pragma unroll
        for (int q = 0; q < 4; ++q)
            fa[t][q] = *(const float4*)(x + (size_t)(a0 + t) * DIM + l16 * 4 + q * 64);

    // wave w: ballot-compact positives of anchor a0+w (global label reads)
    {
        const int li = labels[a0 + wid];
        int base = 0;
        #pragma unroll
        for (int c = 0; c < 6; ++c) {
            const bool m = (labels[c * 64 + lane] == li);
            const unsigned long long mk = __ballot(m);
            const int pre = __popcll(mk & ((1ull << lane) - 1ull));
            const int p = base + pre;
            if (m && p < MAXK) kidx[wid][p] = c * 64 + lane;
            base += __popcll(mk);          // wave-uniform
        }
        if (lane == 0) nk_sh[wid] = (base > MAXK) ? MAXK : base;
    }
    __syncthreads();

    // slice dots: 16 rows/block-iter; JS=24 -> iter 0 full, iter 1 half (guard)
    #pragma unroll
    for (int u = 0; u < 2; ++u) {
        const int rl = u * 16 + wid * 4 + sub;           // 0..31, valid < 24
        if (rl < JS) {
            const float* xr = x + (size_t)(s * JS + rl) * DIM + l16 * 4;
            float4 rx[4];
            #pragma unroll
            for (int q = 0; q < 4; ++q) rx[q] = *(const float4*)(xr + q * 64);
            #pragma unroll
            for (int t = 0; t < GA; ++t) {
                float acc = 0.f;
                #pragma unroll
                for (int q = 0; q < 4; ++q) {
                    const float d0 = rx[q].x - fa[t][q].x, d1 = rx[q].y - fa[t][q].y,
                                d2 = rx[q].z - fa[t][q].z, d3 = rx[q].w - fa[t][q].w;
                    acc += d0*d0 + d1*d1 + d2*d2 + d3*d3;
                }
                #pragma unroll
                for (int m = 1; m < 16; m <<= 1) acc += __shfl_xor(acc, m, 64);
                if (l16 == 0) dj[t][rl] = acc;
            }
        }
    }

    // positive dots: 16 groups (wid,sub) cover each anchor's list (1 iter typ.)
    #pragma unroll
    for (int a = 0; a < GA; ++a) {
        const int nk = nk_sh[a];
        for (int t0 = 0; t0 < nk; t0 += 16) {
            const int t = t0 + wid * 4 + sub;
            if (t < nk) {                    // whole 16-lane group together
                const float* xr = x + (size_t)kidx[a][t] * DIM + l16 * 4;
                float acc = 0.f;
                #pragma unroll
                for (int q = 0; q < 4; ++q) {
                    const float4 rv = *(const float4*)(xr + q * 64);
                    const float d0 = rv.x - fa[a][q].x, d1 = rv.y - fa[a][q].y,
                                d2 = rv.z - fa[a][q].z, d3 = rv.w - fa[a][q].w;
                    acc += d0*d0 + d1*d1 + d2*d2 + d3*d3;
                }
                #pragma unroll
                for (int m = 1; m < 16; m <<= 1) acc += __shfl_xor(acc, m, 64);
                if (l16 == 0) dk[a][t] = acc;
            }
        }
    }
    __syncthreads();

    // hinge: 96 (a, jl) pairs, threads 0..95 (waves 0-1)
    float num = 0.f, cnt = 0.f;
    if (tid < GA * JS) {
        const int a  = tid / JS;
        const int jl = tid % JS;
        const int li = lab[a0 + a];
        if (lab[s * JS + jl] != li) {
            const int nk = nk_sh[a];
            const float b = dj[a][jl] - MARGIN;
            for (int t = 0; t < nk; ++t) {
                const float h = b + dk[a][t];
                num += (h > 0.f) ? h : 0.f;
            }
            cnt = (float)nk;
        }
    }
    if (wid < 2) {
        num = wave_red_sum(num);
        cnt = wave_red_sum(cnt);
        if (lane == 0) { wnum[wid] = num; wcnt[wid] = cnt; }
    }
    __syncthreads();
    if (tid == 0)
        partial[blockIdx.y * gridDim.x + blockIdx.x] =
            make_float2(wnum[0] + wnum[1], wcnt[0] + wcnt[1]);
}

__global__ __launch_bounds__(256) void triplet_finalize(const float2* __restrict__ partial,
                                                        float* __restrict__ out) {
    const int tid = threadIdx.x, lane = tid & 63, wid = tid >> 6;
    __shared__ float wnum[4], wcnt[4];
    float n = 0.f, c = 0.f;
    for (int p = tid; p < NBLK; p += 256) {
        const float2 v = partial[p];
        n += v.x; c += v.y;
    }
    n = wave_red_sum(n);
    c = wave_red_sum(c);
    if (lane == 0) { wnum[wid] = n; wcnt[wid] = c; }
    __syncthreads();
    if (tid == 0)
        out[0] = (wnum[0] + wnum[1] + wnum[2] + wnum[3]) /
                 (wcnt[0] + wcnt[1] + wcnt[2] + wcnt[3]);
}

extern "C" void kernel_launch(void* const* d_in, const int* in_sizes, int n_in,
                              void* d_out, int out_size, void* d_ws, size_t ws_size,
                              hipStream_t stream) {
    const float* x      = (const float*)d_in[0];
    const int*   labels = (const int*)d_in[1];
    float*       out    = (float*)d_out;

    float2* partial = (float2*)d_ws;

    dim3 grid(NGRP, SPLIT);
    triplet_main<<<grid, 256, 0, stream>>>(x, labels, partial);
    triplet_finalize<<<1, 256, 0, stream>>>(partial, out);
}

// Round 12
// 22.941 us; speedup vs baseline: 2.5328x; 1.0610x over previous
//
#include <hip/hip_runtime.h>

#define NPTS   384
#define DIM    256
#define GA     4              // anchors per K2 block
#define NGRP   (NPTS/GA)      // 96 anchor groups
#define SPLIT  16             // j-slices
#define JS     (NPTS/SPLIT)   // 24 j's per K2 block
#define NBLK   (NGRP*SPLIT)   // 1536 blocks = 6/CU
#define MAXK   64             // cap on same-class count (expected ~12)
#define MARGIN 1.0f

__device__ __forceinline__ float wave_red_sum(float p) {
    #pragma unroll
    for (int m = 1; m < 64; m <<= 1) p += __shfl_xor(p, m, 64);
    return p;
}

// K1: one wave per anchor. Ballot-compact positives, 16-lane-group dots,
// write posd[i][t] = d(i,k_t) - MARGIN and nk[i]. Kills the SPLIT-fold
// positive redundancy of the fused family (computed ONCE per anchor).
__global__ __launch_bounds__(64) void triplet_pos(const float* __restrict__ x,
                                                  const int* __restrict__ labels,
                                                  float* __restrict__ posd,
                                                  int* __restrict__ nkarr) {
    const int i    = blockIdx.x;
    const int lane = threadIdx.x;
    const int sub  = lane >> 4;
    const int l16  = lane & 15;

    __shared__ int kidx[MAXK];

    const int li = labels[i];
    int base = 0;
    #pragma unroll
    for (int c = 0; c < 6; ++c) {
        const bool m = (labels[c * 64 + lane] == li);
        const unsigned long long mk = __ballot(m);
        const int pre = __popcll(mk & ((1ull << lane) - 1ull));
        const int p = base + pre;
        if (m && p < MAXK) kidx[p] = c * 64 + lane;
        base += __popcll(mk);              // wave-uniform
    }
    const int nk = (base > MAXK) ? MAXK : base;

    float4 fa[4];
    #pragma unroll
    for (int q = 0; q < 4; ++q)
        fa[q] = *(const float4*)(x + (size_t)i * DIM + l16 * 4 + q * 64);

    // 4 pos rows per iteration (16-lane groups); ~3 iterations typical
    for (int t0 = 0; t0 < nk; t0 += 4) {
        const int t = t0 + sub;
        if (t < nk) {
            const float* xr = x + (size_t)kidx[t] * DIM + l16 * 4;
            float acc = 0.f;
            #pragma unroll
            for (int q = 0; q < 4; ++q) {
                const float4 a = *(const float4*)(xr + q * 64);
                const float d0 = a.x - fa[q].x, d1 = a.y - fa[q].y,
                            d2 = a.z - fa[q].z, d3 = a.w - fa[q].w;
                acc += d0*d0 + d1*d1 + d2*d2 + d3*d3;
            }
            #pragma unroll
            for (int m = 1; m < 16; m <<= 1) acc += __shfl_xor(acc, m, 64);
            if (l16 == 0) posd[(size_t)i * MAXK + t] = acc - MARGIN;
        }
    }
    if (lane == 0) nkarr[i] = nk;
}

// K2: block (g, s) = anchors 4g..4g+3 x j-slice s (24 rows). No ballot, no
// positive dots, no label staging — prologue is frag loads + posd->LDS stage.
__global__ __launch_bounds__(256) void triplet_main(const float* __restrict__ x,
                                                    const int* __restrict__ labels,
                                                    const float* __restrict__ posd,
                                                    const int* __restrict__ nkarr,
                                                    float2* __restrict__ partial) {
    const int g    = blockIdx.x;
    const int s    = blockIdx.y;
    const int tid  = threadIdx.x;
    const int lane = tid & 63;
    const int wid  = tid >> 6;
    const int sub  = lane >> 4;
    const int l16  = lane & 15;
    const int a0   = g * GA;

    __shared__ float dj[GA][JS];
    __shared__ float kd[GA][MAXK];
    __shared__ int   nk4[GA];
    __shared__ float wnum[2], wcnt[2];

    // stage positives (one coalesced round: 256 threads = 4 anchors x 64 slots)
    kd[tid >> 6][tid & 63] = posd[(size_t)(a0 + (tid >> 6)) * MAXK + (tid & 63)];
    if (tid < GA) nk4[tid] = nkarr[a0 + tid];

    // anchor fragments
    float4 fa[GA][4];
    #pragma unroll
    for (int t = 0; t < GA; ++t)
        #pragma unroll
        for (int q = 0; q < 4; ++q)
            fa[t][q] = *(const float4*)(x + (size_t)(a0 + t) * DIM + l16 * 4 + q * 64);

    // slice dots: 16 rows/iter; JS=24 -> iter 0 full, iter 1 half (guarded)
    #pragma unroll
    for (int u = 0; u < 2; ++u) {
        const int rl = u * 16 + wid * 4 + sub;           // 0..31, valid < 24
        if (rl < JS) {
            const float* xr = x + (size_t)(s * JS + rl) * DIM + l16 * 4;
            float4 rx[4];
            #pragma unroll
            for (int q = 0; q < 4; ++q) rx[q] = *(const float4*)(xr + q * 64);
            #pragma unroll
            for (int t = 0; t < GA; ++t) {
                float acc = 0.f;
                #pragma unroll
                for (int q = 0; q < 4; ++q) {
                    const float d0 = rx[q].x - fa[t][q].x, d1 = rx[q].y - fa[t][q].y,
                                d2 = rx[q].z - fa[t][q].z, d3 = rx[q].w - fa[t][q].w;
                    acc += d0*d0 + d1*d1 + d2*d2 + d3*d3;
                }
                #pragma unroll
                for (int m = 1; m < 16; m <<= 1) acc += __shfl_xor(acc, m, 64);
                if (l16 == 0) dj[t][rl] = acc;
            }
        }
    }
    __syncthreads();

    // hinge: 96 (a, jl) pairs on waves 0-1; posd already has -MARGIN baked
    float num = 0.f, cnt = 0.f;
    if (tid < GA * JS) {
        const int a  = tid / JS;
        const int jl = tid % JS;
        if (labels[s * JS + jl] != labels[a0 + a]) {
            const int nk = nk4[a];
            const float b = dj[a][jl];
            for (int t = 0; t < nk; ++t) {
                const float h = b + kd[a][t];
                num += (h > 0.f) ? h : 0.f;
            }
            cnt = (float)nk;
        }
    }
    if (wid < 2) {
        num = wave_red_sum(num);
        cnt = wave_red_sum(cnt);
        if (lane == 0) { wnum[wid] = num; wcnt[wid] = cnt; }
    }
    __syncthreads();
    if (tid == 0)
        partial[blockIdx.y * gridDim.x + blockIdx.x] =
            make_float2(wnum[0] + wnum[1], wcnt[0] + wcnt[1]);
}

__global__ __launch_bounds__(256) void triplet_finalize(const float2* __restrict__ partial,
                                                        float* __restrict__ out) {
    const int tid = threadIdx.x, lane = tid & 63, wid = tid >> 6;
    __shared__ float wnum[4], wcnt[4];
    float n = 0.f, c = 0.f;
    for (int p = tid; p < NBLK; p += 256) {
        const float2 v = partial[p];
        n += v.x; c += v.y;
    }
    n = wave_red_sum(n);
    c = wave_red_sum(c);
    if (lane == 0) { wnum[wid] = n; wcnt[wid] = c; }
    __syncthreads();
    if (tid == 0)
        out[0] = (wnum[0] + wnum[1] + wnum[2] + wnum[3]) /
                 (wcnt[0] + wcnt[1] + wcnt[2] + wcnt[3]);
}

extern "C" void kernel_launch(void* const* d_in, const int* in_sizes, int n_in,
                              void* d_out, int out_size, void* d_ws, size_t ws_size,
                              hipStream_t stream) {
    const float* x      = (const float*)d_in[0];
    const int*   labels = (const int*)d_in[1];
    float*       out    = (float*)d_out;

    float*  posd    = (float*)d_ws;                                   // 98 KB
    int*    nkarr   = (int*)((char*)d_ws + (size_t)NPTS * MAXK * sizeof(float));
    float2* partial = (float2*)((char*)nkarr + NPTS * sizeof(int));   // 12 KB

    triplet_pos<<<NPTS, 64, 0, stream>>>(x, labels, posd, nkarr);
    dim3 grid(NGRP, SPLIT);
    triplet_main<<<grid, 256, 0, stream>>>(x, labels, posd, nkarr, partial);
    triplet_finalize<<<1, 256, 0, stream>>>(partial, out);
}